// Round 6
// baseline (325.077 us; speedup 1.0000x reference)
//
#include <hip/hip_runtime.h>
#include <math.h>

#define BATCH  2
#define SEQ    2048
#define DMODEL 1024
#define NH     16
#define HD     64
#define NQKV   3072
#define ROWS   (BATCH*SEQ)
#define QSCALE 0.18033688f   // 0.125 * log2(e): QK^T scores land in log2 domain

typedef unsigned short u16;
typedef unsigned int   u32;
typedef __bf16 bf16x8 __attribute__((ext_vector_type(8)));
typedef float  f32x4  __attribute__((ext_vector_type(4)));

typedef const __attribute__((address_space(1))) void* gptr_t;
typedef __attribute__((address_space(3))) void* lptr_t;

__device__ __forceinline__ void gload16(lptr_t l, const void* g) {
    __builtin_amdgcn_global_load_lds((gptr_t)g, l, 16, 0, 0);
}

__device__ __forceinline__ u16 f2bf(float f) {          // RNE f32->bf16
    unsigned int u = __float_as_uint(f);
    u += 0x7FFFu + ((u >> 16) & 1u);
    return (u16)(u >> 16);
}
__device__ __forceinline__ float bf2f(u16 v) {
    return __uint_as_float(((unsigned int)v) << 16);
}
__device__ __forceinline__ u32 pk2(float lo, float hi) { // pack 2 f32 -> 2 bf16
#if __has_builtin(__builtin_amdgcn_cvt_pk_bf16_f32)
    typedef __bf16 bf16x2 __attribute__((ext_vector_type(2)));
    union { bf16x2 v; u32 u; } cv;
    cv.v = __builtin_amdgcn_cvt_pk_bf16_f32(lo, hi);
    return cv.u;
#else
    return (u32)f2bf(lo) | ((u32)f2bf(hi) << 16);
#endif
}
__device__ __forceinline__ float fexp2(float x) {
#if __has_builtin(__builtin_amdgcn_exp2f)
    return __builtin_amdgcn_exp2f(x);
#else
    return exp2f(x);
#endif
}

// ---------------------------------------------------------------------------
// fused f32 -> bf16 for x, qkv_w, out_w
// ---------------------------------------------------------------------------
__global__ void f2bf3_kernel(const float* __restrict__ a, int na,
                             const float* __restrict__ b, int nb,
                             const float* __restrict__ c, int nc,
                             u16* __restrict__ oa, u16* __restrict__ ob,
                             u16* __restrict__ oc)
{
    int i = (blockIdx.x * 256 + threadIdx.x) * 4;
    const float* s; u16* d; int base;
    if (i < na)                { s = a; d = oa; base = i; }
    else if (i < na + nb)      { s = b; d = ob; base = i - na; }
    else if (i < na + nb + nc) { s = c; d = oc; base = i - na - nb; }
    else return;
    float4 v = *(const float4*)(s + base);
    u16 o[4] = { f2bf(v.x), f2bf(v.y), f2bf(v.z), f2bf(v.w) };
    *(uint2*)(d + base) = *(const uint2*)o;
}

// ---------------------------------------------------------------------------
// wtab[h][d] = exp(-max(p,.01)*log1p(max(a,.01)*d))  (multiplicative bias)
// ---------------------------------------------------------------------------
__global__ void wtab_kernel(const float* __restrict__ bias_p,
                            const float* __restrict__ bias_a,
                            float* __restrict__ wtab)
{
    int idx = blockIdx.x * 256 + threadIdx.x;
    int h = idx >> 11;
    int d = idx & (SEQ - 1);
    float p = fmaxf(bias_p[h], 0.01f);
    float a = fmaxf(bias_a[h], 0.01f);
    wtab[idx] = __expf(-p * log1pf(a * (float)d));
}

// cs_tab[(s*32+d)*2] = cos(s*freqs[d]), +1 = sin
__global__ void rope_table_kernel(const float* __restrict__ freqs, float* __restrict__ tab)
{
    int idx = blockIdx.x * 256 + threadIdx.x;   // SEQ*32
    int s = idx >> 5, d = idx & 31;
    float sn, cs;
    sincosf((float)s * freqs[d], &sn, &cs);
    tab[idx * 2]     = cs;
    tab[idx * 2 + 1] = sn;
}

// ---------------------------------------------------------------------------
// QKV GEMM with fused RoPE + layout epilogue. C[M=4096][N=3072] tile 128x128.
// Each wave's 64-col quadrant is exactly one (t,h): t=col/1024, h=(col/64)%16.
// t=0: RoPE+QSCALE -> Qb[b][h][s][d]; t=1: RoPE -> Kb; t=2: transpose ->
// Vt[b][h][d][s] (b64 stores, r=0..3 pack along s).
// ---------------------------------------------------------------------------
__global__ __launch_bounds__(256) void gemm_qkv(
    const u16* __restrict__ A, const u16* __restrict__ B,
    const float* __restrict__ cs_tab,
    u16* __restrict__ Qb, u16* __restrict__ Kb, u16* __restrict__ Vt)
{
    const int M = ROWS, N = NQKV, K = DMODEL;
    __shared__ __align__(16) u16 As[128][32];
    __shared__ __align__(16) u16 Bs[128][32];
    const int tid  = threadIdx.x;
    const int wave = tid >> 6, lane = tid & 63;
    const int quad = lane >> 4, l16 = lane & 15;
    const int wrow = (wave >> 1) * 64, wcol = (wave & 1) * 64;
    const int bm = blockIdx.x * 128, bn = blockIdx.y * 128;

    const int srow = lane >> 2;                       // 0..15
    const int scol = ((lane & 3) ^ (srow & 3)) * 8;   // swizzled chunk (u16)
    const int fsw = (quad ^ (l16 & 3)) * 8;           // frag read swizzle

    f32x4 acc[4][4];
#pragma unroll
    for (int i = 0; i < 4; ++i)
#pragma unroll
        for (int j = 0; j < 4; ++j) acc[i][j] = (f32x4){0.f,0.f,0.f,0.f};

    const u16* Ag0 = A + (size_t)(bm + wave*32 + srow)      * K + scol;
    const u16* Ag1 = A + (size_t)(bm + wave*32 + 16 + srow) * K + scol;
    const u16* Bg0 = B + (size_t)(bn + wave*32 + srow)      * K + scol;
    const u16* Bg1 = B + (size_t)(bn + wave*32 + 16 + srow) * K + scol;

    for (int k0 = 0; k0 < K; k0 += 32) {
        __syncthreads();
        gload16((lptr_t)&As[wave*32][0],      Ag0 + k0);
        gload16((lptr_t)&As[wave*32 + 16][0], Ag1 + k0);
        gload16((lptr_t)&Bs[wave*32][0],      Bg0 + k0);
        gload16((lptr_t)&Bs[wave*32 + 16][0], Bg1 + k0);
        __syncthreads();
        bf16x8 af[4], bfr[4];
#pragma unroll
        for (int i = 0; i < 4; ++i)
            af[i] = *(const bf16x8*)&As[wrow + i*16 + l16][fsw];
#pragma unroll
        for (int j = 0; j < 4; ++j)
            bfr[j] = *(const bf16x8*)&Bs[wcol + j*16 + l16][fsw];
#pragma unroll
        for (int i = 0; i < 4; ++i)
#pragma unroll
            for (int j = 0; j < 4; ++j)
                acc[i][j] = __builtin_amdgcn_mfma_f32_16x16x32_bf16(af[i], bfr[j], acc[i][j], 0, 0, 0);
    }

    // ---- fused epilogue ----
    const int tcol = (bn + wcol) >> 6;          // global 64-col index, 0..47
    const int t = tcol >> 4, h = tcol & 15;     // tensor (q/k/v), head
    const int bq = bm >> 11;                    // batch (tile never crosses)
    const int sb = (bm & (SEQ - 1)) + wrow;     // s base of this quadrant
    const size_t hb = (size_t)(bq * NH + h) * SEQ * HD;

    if (t == 2) {
        // V: Vt[b][h][d][s], pack 4 consecutive s (r=0..3) into b64
#pragma unroll
        for (int i = 0; i < 4; ++i) {
            const int s = sb + i*16 + quad*4;
#pragma unroll
            for (int j = 0; j < 4; ++j) {
                const int d = j*16 + l16;
                uint2 pv = make_uint2(pk2(acc[i][j][0], acc[i][j][1]),
                                      pk2(acc[i][j][2], acc[i][j][3]));
                *(uint2*)&Vt[hb + (size_t)d * SEQ + s] = pv;
            }
        }
    } else {
        const float sc = (t == 0) ? QSCALE : 1.0f;
        u16* dstb = ((t == 0) ? Qb : Kb) + hb;
#pragma unroll
        for (int i = 0; i < 4; ++i) {
#pragma unroll
            for (int r = 0; r < 4; ++r) {
                const int s = sb + i*16 + quad*4 + r;
                const float2* ct = (const float2*)(cs_tab + ((size_t)s * 32 + l16) * 2);
                float2 cs0 = ct[0];     // freq idx l16
                float2 cs1 = ct[16];    // freq idx l16+16
                float a0 = acc[i][0][r], a1 = acc[i][1][r];
                float a2 = acc[i][2][r], a3 = acc[i][3][r];
                u16* dst = dstb + (size_t)s * HD;
                dst[l16]      = f2bf((a0*cs0.x - a2*cs0.y) * sc);
                dst[16 + l16] = f2bf((a1*cs1.x - a3*cs1.y) * sc);
                dst[32 + l16] = f2bf((a0*cs0.y + a2*cs0.x) * sc);
                dst[48 + l16] = f2bf((a1*cs1.y + a3*cs1.x) * sc);
            }
        }
    }
}

// ---------------------------------------------------------------------------
// bf16 NT GEMM (out-projection): C[M,N] f32 = A[M,K] * B[N,K]^T.
// ---------------------------------------------------------------------------
__global__ __launch_bounds__(256) void gemm_out(
    const u16* __restrict__ A, const u16* __restrict__ B,
    float* __restrict__ Cout, int M, int N, int K)
{
    __shared__ __align__(16) u16 As[128][32];
    __shared__ __align__(16) u16 Bs[128][32];
    const int tid  = threadIdx.x;
    const int wave = tid >> 6, lane = tid & 63;
    const int quad = lane >> 4, l16 = lane & 15;
    const int wrow = (wave >> 1) * 64, wcol = (wave & 1) * 64;
    const int bm = blockIdx.x * 128, bn = blockIdx.y * 128;

    const int srow = lane >> 2;
    const int scol = ((lane & 3) ^ (srow & 3)) * 8;
    const int fsw = (quad ^ (l16 & 3)) * 8;

    f32x4 acc[4][4];
#pragma unroll
    for (int i = 0; i < 4; ++i)
#pragma unroll
        for (int j = 0; j < 4; ++j) acc[i][j] = (f32x4){0.f,0.f,0.f,0.f};

    const u16* Ag0 = A + (size_t)(bm + wave*32 + srow)      * K + scol;
    const u16* Ag1 = A + (size_t)(bm + wave*32 + 16 + srow) * K + scol;
    const u16* Bg0 = B + (size_t)(bn + wave*32 + srow)      * K + scol;
    const u16* Bg1 = B + (size_t)(bn + wave*32 + 16 + srow) * K + scol;

    for (int k0 = 0; k0 < K; k0 += 32) {
        __syncthreads();
        gload16((lptr_t)&As[wave*32][0],      Ag0 + k0);
        gload16((lptr_t)&As[wave*32 + 16][0], Ag1 + k0);
        gload16((lptr_t)&Bs[wave*32][0],      Bg0 + k0);
        gload16((lptr_t)&Bs[wave*32 + 16][0], Bg1 + k0);
        __syncthreads();
        bf16x8 af[4], bfr[4];
#pragma unroll
        for (int i = 0; i < 4; ++i)
            af[i] = *(const bf16x8*)&As[wrow + i*16 + l16][fsw];
#pragma unroll
        for (int j = 0; j < 4; ++j)
            bfr[j] = *(const bf16x8*)&Bs[wcol + j*16 + l16][fsw];
#pragma unroll
        for (int i = 0; i < 4; ++i)
#pragma unroll
            for (int j = 0; j < 4; ++j)
                acc[i][j] = __builtin_amdgcn_mfma_f32_16x16x32_bf16(af[i], bfr[j], acc[i][j], 0, 0, 0);
    }

#pragma unroll
    for (int i = 0; i < 4; ++i)
#pragma unroll
        for (int j = 0; j < 4; ++j) {
            int col = bn + wcol + j*16 + l16;
#pragma unroll
            for (int r = 0; r < 4; ++r) {
                int row = bm + wrow + i*16 + quad*4 + r;
                Cout[(size_t)row * N + col] = acc[i][j][r];
            }
        }
}

// ---------------------------------------------------------------------------
// MFMA flash attention v4: MFMA fragments direct from global (no K/V LDS).
// Block = (64 q, h, b), 4 waves; wave w owns keys w*16.. of each 64-key tile.
// S^T = K*Q^T (scores in B-operand layout over keys); P round-trips LDS for
// the A-operand transform; V frags read straight from Vt[b][h][d][s] (each
// 64-lane b128 request = 16 fully-used 64B lines); bias = wave-private
// multiplicative window (no fill barrier). 2 barriers/tile (Ps only).
// ---------------------------------------------------------------------------
__global__ __launch_bounds__(256) void attn_mfma(
    const u16* __restrict__ Qb, const u16* __restrict__ Kb,
    const u16* __restrict__ Vt, const float* __restrict__ wtab,
    u16* __restrict__ attn_bf)
{
    __shared__ __align__(16) u16 Ps[64][72];   // [q][key], padded
    __shared__ u32 ws2[4][128];                // per-wave bias pair window
    __shared__ float lred[4][64];
    __shared__ float linv[64];

    const int tid = threadIdx.x;
    const int wave = tid >> 6, lane = tid & 63;
    const int quad = lane >> 4, l16 = lane & 15;
    const int q0 = blockIdx.x * 64, h = blockIdx.y, b = blockIdx.z;

    const u16* Qh = Qb + (size_t)(b * NH + h) * SEQ * HD;
    const u16* Kh = Kb + (size_t)(b * NH + h) * SEQ * HD;
    const u16* Vh = Vt + (size_t)(b * NH + h) * HD * SEQ;
    const float* wh = wtab + h * SEQ;

    // Q fragments (B-operand of S^T): all 64 q rows per wave, loop-invariant
    bf16x8 qf0[4], qf1[4];
#pragma unroll
    for (int qj = 0; qj < 4; ++qj) {
        const u16* qr = Qh + (size_t)(q0 + qj*16 + l16) * HD + quad * 8;
        qf0[qj] = *(const bf16x8*)qr;
        qf1[qj] = *(const bf16x8*)(qr + 32);
    }

    const u16* kptr = Kh + (size_t)(wave*16 + l16) * HD + quad * 8;
    const int mb0 = 63 + l16 - wave*16 - quad*4 - 3;   // w-window base (>=0)

    float l_p[4] = {0.f, 0.f, 0.f, 0.f};
    f32x4 o[4];
#pragma unroll
    for (int j = 0; j < 4; ++j) o[j] = (f32x4){0.f,0.f,0.f,0.f};

    for (int kt = 0; kt < SEQ / 64; ++kt) {
        const int k0 = kt * 64;
        __syncthreads();               // prior tile's Ps reads complete

        // wave-private bias window: lane fills entries lane, lane+64
#pragma unroll
        for (int u0 = 0; u0 < 2; ++u0) {
            int u = lane + u0*64;
            int i0 = (q0 - k0 - 63) + u;
            int a0 = i0 < 0 ? -i0 : i0;  if (a0 > SEQ-1) a0 = SEQ-1;
            int i1 = i0 + 1;
            int a1 = i1 < 0 ? -i1 : i1;  if (a1 > SEQ-1) a1 = SEQ-1;
            ws2[wave][u] = pk2(wh[a0], wh[a1]);
        }

        // global fragment loads (vmem pipe; latency hidden behind QK+softmax)
        bf16x8 kf0 = *(const bf16x8*)(kptr + (size_t)k0 * HD);
        bf16x8 kf1 = *(const bf16x8*)(kptr + (size_t)k0 * HD + 32);
        bf16x8 vf0[4], vf1[4];
#pragma unroll
        for (int j = 0; j < 4; ++j) {
            const u16* vp = Vh + (size_t)(j*16 + l16) * SEQ + k0 + quad * 8;
            vf0[j] = *(const bf16x8*)vp;
            vf1[j] = *(const bf16x8*)(vp + 32);
        }

        // ---- S^T = K * Q^T for this wave's 16 keys; softmax; P write ----
#pragma unroll
        for (int qj = 0; qj < 4; ++qj) {
            f32x4 z = (f32x4){0.f,0.f,0.f,0.f};
            z = __builtin_amdgcn_mfma_f32_16x16x32_bf16(kf0, qf0[qj], z, 0, 0, 0);
            z = __builtin_amdgcn_mfma_f32_16x16x32_bf16(kf1, qf1[qj], z, 0, 0, 0);
            const int mbase = mb0 + qj*16;
            u32 pA = ws2[wave][mbase], pB = ws2[wave][mbase + 2];
            float w3 = __uint_as_float(pA << 16);
            float w2 = __uint_as_float(pA & 0xffff0000u);
            float w1 = __uint_as_float(pB << 16);
            float w0 = __uint_as_float(pB & 0xffff0000u);
            float e0 = fexp2(z[0]) * w0, e1 = fexp2(z[1]) * w1;
            float e2 = fexp2(z[2]) * w2, e3 = fexp2(z[3]) * w3;
            l_p[qj] += (e0 + e1) + (e2 + e3);
            *(uint2*)&Ps[qj*16 + l16][wave*16 + quad*4] =
                make_uint2(pk2(e0, e1), pk2(e2, e3));
        }
        __syncthreads();               // P visible to all waves

        // ---- PV: O[q=wave rows][d] += P * V ----
        bf16x8 pf0 = *(const bf16x8*)&Ps[wave*16 + l16][quad*8];
        bf16x8 pf1 = *(const bf16x8*)&Ps[wave*16 + l16][32 + quad*8];
#pragma unroll
        for (int j = 0; j < 4; ++j) {
            o[j] = __builtin_amdgcn_mfma_f32_16x16x32_bf16(pf0, vf0[j], o[j], 0, 0, 0);
            o[j] = __builtin_amdgcn_mfma_f32_16x16x32_bf16(pf1, vf1[j], o[j], 0, 0, 0);
        }
    }

    // ---- epilogue: reduce l (quads via shfl, waves via LDS), store ----
#pragma unroll
    for (int qj = 0; qj < 4; ++qj) {
        float l = l_p[qj];
        l += __shfl_xor(l, 16);
        l += __shfl_xor(l, 32);
        if (quad == 0) lred[wave][qj*16 + l16] = l;
    }
    __syncthreads();
    if (tid < 64)
        linv[tid] = 1.0f / (lred[0][tid] + lred[1][tid] + lred[2][tid] + lred[3][tid]);
    __syncthreads();
#pragma unroll
    for (int r = 0; r < 4; ++r) {
        const int q = wave*16 + quad*4 + r;
        float inv = linv[q];
        u16* dst = attn_bf + (size_t)(b * SEQ + q0 + q) * DMODEL + h * HD;
#pragma unroll
        for (int j = 0; j < 4; ++j)
            dst[j*16 + l16] = f2bf(o[j][r] * inv);
    }
}

// ---------------------------------------------------------------------------
extern "C" void kernel_launch(void* const* d_in, const int* in_sizes, int n_in,
                              void* d_out, int out_size, void* d_ws, size_t ws_size,
                              hipStream_t stream)
{
    (void)in_sizes; (void)n_in; (void)out_size; (void)ws_size;
    const float* x      = (const float*)d_in[0];
    const float* qkv_w  = (const float*)d_in[1];
    const float* out_w  = (const float*)d_in[2];
    const float* bias_p = (const float*)d_in[3];
    const float* bias_a = (const float*)d_in[4];
    const float* freqs  = (const float*)d_in[5];
    float* out = (float*)d_out;

    // ws layout (bytes):
    //   [0, 8M)       attn_bf [4096][1024] bf16
    //   [8M, 16M)     Qb      [2][16][2048][64] bf16
    //   [24M, 32M)    x_bf    [4096][1024] bf16
    //   [32M, 38M)    w1_bf   [3072][1024] bf16
    //   [38M, 40M)    w2_bf   [1024][1024] bf16
    //   [40M, 48M)    Kb      [2][16][2048][64] bf16
    //   [48M, 56M)    Vt      [2][16][64][2048] bf16
    //   [56M, +128K)  wtab    [16][2048] f32 (exp of bias)
    //   [+128K,+640K) cs_tab  [2048][32][2] f32
    char* ws = (char*)d_ws;
    u16*   attn_bf = (u16*)ws;
    u16*   Qb      = (u16*)(ws + 8388608);
    u16*   x_bf    = (u16*)(ws + 25165824);
    u16*   w1_bf   = (u16*)(ws + 33554432);
    u16*   w2_bf   = (u16*)(ws + 39845888);
    u16*   Kb      = (u16*)(ws + 41943040);
    u16*   Vt      = (u16*)(ws + 50331648);
    float* wtab    = (float*)(ws + 58720256);
    float* cs_tab  = (float*)(ws + 58720256 + 131072);

    const int na = ROWS*DMODEL, nb = NQKV*DMODEL, nc = DMODEL*DMODEL;
    f2bf3_kernel<<<dim3((na+nb+nc)/1024), 256, 0, stream>>>(x, na, qkv_w, nb, out_w, nc,
                                                            x_bf, w1_bf, w2_bf);
    rope_table_kernel<<<dim3(SEQ*32/256), 256, 0, stream>>>(freqs, cs_tab);
    wtab_kernel<<<dim3(NH*SEQ/256), 256, 0, stream>>>(bias_p, bias_a, wtab);

    gemm_qkv<<<dim3(ROWS/128, NQKV/128), 256, 0, stream>>>(x_bf, w1_bf, cs_tab, Qb, Kb, Vt);
    attn_mfma<<<dim3(SEQ/64, NH, BATCH), 256, 0, stream>>>(Qb, Kb, Vt, wtab, attn_bf);
    gemm_out<<<dim3(ROWS/128, DMODEL/128), 256, 0, stream>>>(attn_bf, w2_bf, out, ROWS, DMODEL, DMODEL);
}

// Round 7
// 229.963 us; speedup vs baseline: 1.4136x; 1.4136x over previous
//
#include <hip/hip_runtime.h>
#include <math.h>

#define BATCH  2
#define SEQ    2048
#define DMODEL 1024
#define NH     16
#define HD     64
#define NQKV   3072
#define ROWS   (BATCH*SEQ)
#define QSCALE 0.18033688f   // 0.125 * log2(e): QK^T scores land in log2 domain

typedef unsigned short u16;
typedef unsigned int   u32;
typedef __bf16 bf16x8 __attribute__((ext_vector_type(8)));
typedef float  f32x4  __attribute__((ext_vector_type(4)));

typedef const __attribute__((address_space(1))) void* gptr_t;
typedef __attribute__((address_space(3))) void* lptr_t;

__device__ __forceinline__ void gload16(lptr_t l, const void* g) {
    __builtin_amdgcn_global_load_lds((gptr_t)g, l, 16, 0, 0);
}

__device__ __forceinline__ u16 f2bf(float f) {          // RNE f32->bf16
    unsigned int u = __float_as_uint(f);
    u += 0x7FFFu + ((u >> 16) & 1u);
    return (u16)(u >> 16);
}
__device__ __forceinline__ float bf2f(u16 v) {
    return __uint_as_float(((unsigned int)v) << 16);
}
__device__ __forceinline__ u32 pk2(float lo, float hi) { // pack 2 f32 -> 2 bf16
#if __has_builtin(__builtin_amdgcn_cvt_pk_bf16_f32)
    typedef __bf16 bf16x2 __attribute__((ext_vector_type(2)));
    union { bf16x2 v; u32 u; } cv;
    cv.v = __builtin_amdgcn_cvt_pk_bf16_f32(lo, hi);
    return cv.u;
#else
    return (u32)f2bf(lo) | ((u32)f2bf(hi) << 16);
#endif
}
__device__ __forceinline__ float fexp2(float x) {
#if __has_builtin(__builtin_amdgcn_exp2f)
    return __builtin_amdgcn_exp2f(x);
#else
    return exp2f(x);
#endif
}

// ---------------------------------------------------------------------------
// fused f32 -> bf16 for x, qkv_w, out_w
// ---------------------------------------------------------------------------
__global__ void f2bf3_kernel(const float* __restrict__ a, int na,
                             const float* __restrict__ b, int nb,
                             const float* __restrict__ c, int nc,
                             u16* __restrict__ oa, u16* __restrict__ ob,
                             u16* __restrict__ oc)
{
    int i = (blockIdx.x * 256 + threadIdx.x) * 4;
    const float* s; u16* d; int base;
    if (i < na)                { s = a; d = oa; base = i; }
    else if (i < na + nb)      { s = b; d = ob; base = i - na; }
    else if (i < na + nb + nc) { s = c; d = oc; base = i - na - nb; }
    else return;
    float4 v = *(const float4*)(s + base);
    u16 o[4] = { f2bf(v.x), f2bf(v.y), f2bf(v.z), f2bf(v.w) };
    *(uint2*)(d + base) = *(const uint2*)o;
}

// ---------------------------------------------------------------------------
// wtab[h][d] = exp(-max(p,.01)*log1p(max(a,.01)*d))  (multiplicative bias)
// ---------------------------------------------------------------------------
__global__ void wtab_kernel(const float* __restrict__ bias_p,
                            const float* __restrict__ bias_a,
                            float* __restrict__ wtab)
{
    int idx = blockIdx.x * 256 + threadIdx.x;
    int h = idx >> 11;
    int d = idx & (SEQ - 1);
    float p = fmaxf(bias_p[h], 0.01f);
    float a = fmaxf(bias_a[h], 0.01f);
    wtab[idx] = __expf(-p * log1pf(a * (float)d));
}

// cs_tab[(s*32+d)*2] = cos(s*freqs[d]), +1 = sin
__global__ void rope_table_kernel(const float* __restrict__ freqs, float* __restrict__ tab)
{
    int idx = blockIdx.x * 256 + threadIdx.x;   // SEQ*32
    int s = idx >> 5, d = idx & 31;
    float sn, cs;
    sincosf((float)s * freqs[d], &sn, &cs);
    tab[idx * 2]     = cs;
    tab[idx * 2 + 1] = sn;
}

// ---------------------------------------------------------------------------
// QKV GEMM with fused RoPE + layout epilogue (verified R6). 128x128 tile.
// Each wave's 64-col quadrant is exactly one (t,h): t=col/1024, h=(col/64)%16.
// t=0: RoPE+QSCALE -> Qb[b][h][s][d]; t=1: RoPE -> Kb; t=2: transpose ->
// Vt[b][h][d][s] (b64 stores, r=0..3 pack along s).
// ---------------------------------------------------------------------------
__global__ __launch_bounds__(256) void gemm_qkv(
    const u16* __restrict__ A, const u16* __restrict__ B,
    const float* __restrict__ cs_tab,
    u16* __restrict__ Qb, u16* __restrict__ Kb, u16* __restrict__ Vt)
{
    const int K = DMODEL;
    __shared__ __align__(16) u16 As[128][32];
    __shared__ __align__(16) u16 Bs[128][32];
    const int tid  = threadIdx.x;
    const int wave = tid >> 6, lane = tid & 63;
    const int quad = lane >> 4, l16 = lane & 15;
    const int wrow = (wave >> 1) * 64, wcol = (wave & 1) * 64;
    const int bm = blockIdx.x * 128, bn = blockIdx.y * 128;

    const int srow = lane >> 2;                       // 0..15
    const int scol = ((lane & 3) ^ (srow & 3)) * 8;   // swizzled chunk (u16)
    const int fsw = (quad ^ (l16 & 3)) * 8;           // frag read swizzle

    f32x4 acc[4][4];
#pragma unroll
    for (int i = 0; i < 4; ++i)
#pragma unroll
        for (int j = 0; j < 4; ++j) acc[i][j] = (f32x4){0.f,0.f,0.f,0.f};

    const u16* Ag0 = A + (size_t)(bm + wave*32 + srow)      * K + scol;
    const u16* Ag1 = A + (size_t)(bm + wave*32 + 16 + srow) * K + scol;
    const u16* Bg0 = B + (size_t)(bn + wave*32 + srow)      * K + scol;
    const u16* Bg1 = B + (size_t)(bn + wave*32 + 16 + srow) * K + scol;

    for (int k0 = 0; k0 < K; k0 += 32) {
        __syncthreads();
        gload16((lptr_t)&As[wave*32][0],      Ag0 + k0);
        gload16((lptr_t)&As[wave*32 + 16][0], Ag1 + k0);
        gload16((lptr_t)&Bs[wave*32][0],      Bg0 + k0);
        gload16((lptr_t)&Bs[wave*32 + 16][0], Bg1 + k0);
        __syncthreads();
        bf16x8 af[4], bfr[4];
#pragma unroll
        for (int i = 0; i < 4; ++i)
            af[i] = *(const bf16x8*)&As[wrow + i*16 + l16][fsw];
#pragma unroll
        for (int j = 0; j < 4; ++j)
            bfr[j] = *(const bf16x8*)&Bs[wcol + j*16 + l16][fsw];
#pragma unroll
        for (int i = 0; i < 4; ++i)
#pragma unroll
            for (int j = 0; j < 4; ++j)
                acc[i][j] = __builtin_amdgcn_mfma_f32_16x16x32_bf16(af[i], bfr[j], acc[i][j], 0, 0, 0);
    }

    // ---- fused epilogue ----
    const int tcol = (bn + wcol) >> 6;          // global 64-col index, 0..47
    const int t = tcol >> 4, h = tcol & 15;     // tensor (q/k/v), head
    const int bq = bm >> 11;                    // batch (tile never crosses)
    const int sb = (bm & (SEQ - 1)) + wrow;     // s base of this quadrant
    const size_t hb = (size_t)(bq * NH + h) * SEQ * HD;

    if (t == 2) {
        // V: Vt[b][h][d][s], pack 4 consecutive s (r=0..3) into b64
#pragma unroll
        for (int i = 0; i < 4; ++i) {
            const int s = sb + i*16 + quad*4;
#pragma unroll
            for (int j = 0; j < 4; ++j) {
                const int d = j*16 + l16;
                uint2 pv = make_uint2(pk2(acc[i][j][0], acc[i][j][1]),
                                      pk2(acc[i][j][2], acc[i][j][3]));
                *(uint2*)&Vt[hb + (size_t)d * SEQ + s] = pv;
            }
        }
    } else {
        const float sc = (t == 0) ? QSCALE : 1.0f;
        u16* dstb = ((t == 0) ? Qb : Kb) + hb;
#pragma unroll
        for (int i = 0; i < 4; ++i) {
#pragma unroll
            for (int r = 0; r < 4; ++r) {
                const int s = sb + i*16 + quad*4 + r;
                const float2* ct = (const float2*)(cs_tab + ((size_t)s * 32 + l16) * 2);
                float2 cs0 = ct[0];     // freq idx l16
                float2 cs1 = ct[16];    // freq idx l16+16
                float a0 = acc[i][0][r], a1 = acc[i][1][r];
                float a2 = acc[i][2][r], a3 = acc[i][3][r];
                u16* dst = dstb + (size_t)s * HD;
                dst[l16]      = f2bf((a0*cs0.x - a2*cs0.y) * sc);
                dst[16 + l16] = f2bf((a1*cs1.x - a3*cs1.y) * sc);
                dst[32 + l16] = f2bf((a0*cs0.y + a2*cs0.x) * sc);
                dst[48 + l16] = f2bf((a1*cs1.y + a3*cs1.x) * sc);
            }
        }
    }
}

// ---------------------------------------------------------------------------
// bf16 NT GEMM (out-projection): C[M,N] f32 = A[M,K] * B[N,K]^T.
// ---------------------------------------------------------------------------
__global__ __launch_bounds__(256) void gemm_out(
    const u16* __restrict__ A, const u16* __restrict__ B,
    float* __restrict__ Cout, int M, int N, int K)
{
    __shared__ __align__(16) u16 As[128][32];
    __shared__ __align__(16) u16 Bs[128][32];
    const int tid  = threadIdx.x;
    const int wave = tid >> 6, lane = tid & 63;
    const int quad = lane >> 4, l16 = lane & 15;
    const int wrow = (wave >> 1) * 64, wcol = (wave & 1) * 64;
    const int bm = blockIdx.x * 128, bn = blockIdx.y * 128;

    const int srow = lane >> 2;
    const int scol = ((lane & 3) ^ (srow & 3)) * 8;
    const int fsw = (quad ^ (l16 & 3)) * 8;

    f32x4 acc[4][4];
#pragma unroll
    for (int i = 0; i < 4; ++i)
#pragma unroll
        for (int j = 0; j < 4; ++j) acc[i][j] = (f32x4){0.f,0.f,0.f,0.f};

    const u16* Ag0 = A + (size_t)(bm + wave*32 + srow)      * K + scol;
    const u16* Ag1 = A + (size_t)(bm + wave*32 + 16 + srow) * K + scol;
    const u16* Bg0 = B + (size_t)(bn + wave*32 + srow)      * K + scol;
    const u16* Bg1 = B + (size_t)(bn + wave*32 + 16 + srow) * K + scol;

    for (int k0 = 0; k0 < K; k0 += 32) {
        __syncthreads();
        gload16((lptr_t)&As[wave*32][0],      Ag0 + k0);
        gload16((lptr_t)&As[wave*32 + 16][0], Ag1 + k0);
        gload16((lptr_t)&Bs[wave*32][0],      Bg0 + k0);
        gload16((lptr_t)&Bs[wave*32 + 16][0], Bg1 + k0);
        __syncthreads();
        bf16x8 af[4], bfr[4];
#pragma unroll
        for (int i = 0; i < 4; ++i)
            af[i] = *(const bf16x8*)&As[wrow + i*16 + l16][fsw];
#pragma unroll
        for (int j = 0; j < 4; ++j)
            bfr[j] = *(const bf16x8*)&Bs[wcol + j*16 + l16][fsw];
#pragma unroll
        for (int i = 0; i < 4; ++i)
#pragma unroll
            for (int j = 0; j < 4; ++j)
                acc[i][j] = __builtin_amdgcn_mfma_f32_16x16x32_bf16(af[i], bfr[j], acc[i][j], 0, 0, 0);
    }

#pragma unroll
    for (int i = 0; i < 4; ++i)
#pragma unroll
        for (int j = 0; j < 4; ++j) {
            int col = bn + wcol + j*16 + l16;
#pragma unroll
            for (int r = 0; r < 4; ++r) {
                int row = bm + wrow + i*16 + quad*4 + r;
                Cout[(size_t)row * N + col] = acc[i][j][r];
            }
        }
}

// ---------------------------------------------------------------------------
// MFMA flash attention v3 (R5, measured 81 us): gload16-staged K/V, swapped
// scores S^T = K*Q^T, packed P writes, multiplicative bias window.
// ---------------------------------------------------------------------------
__global__ __launch_bounds__(256) void attn_mfma(
    const u16* __restrict__ Qb, const u16* __restrict__ Kb,
    const u16* __restrict__ Vt, const float* __restrict__ wtab,
    u16* __restrict__ attn_bf)
{
    __shared__ __align__(16) u16 Ks[64*64];    // [key][d], chunk-swizzled
    __shared__ __align__(16) u16 Vs[64*64];    // [d][key], chunk-swizzled
    __shared__ __align__(16) u16 Ps[64][72];   // [q][key], padded
    __shared__ u32 ws2[128];                   // packed {w[m], w[m+1]}
    __shared__ float lred[4][64];
    __shared__ float linv[64];

    const int tid = threadIdx.x;
    const int wave = tid >> 6, lane = tid & 63;
    const int quad = lane >> 4, l16 = lane & 15;
    const int q0 = blockIdx.x * 64, h = blockIdx.y, b = blockIdx.z;

    const u16* Qh = Qb + (size_t)(b * NH + h) * SEQ * HD;
    const u16* Kh = Kb + (size_t)(b * NH + h) * SEQ * HD;
    const u16* Vh = Vt + (size_t)(b * NH + h) * HD * SEQ;
    const float* wh = wtab + h * SEQ;

    // Q fragments (B-operand of S^T): all 64 q rows per wave, in registers
    bf16x8 qf0[4], qf1[4];
#pragma unroll
    for (int qj = 0; qj < 4; ++qj) {
        const u16* qr = Qh + (size_t)(q0 + qj*16 + l16) * HD + quad * 8;
        qf0[qj] = *(const bf16x8*)qr;
        qf1[qj] = *(const bf16x8*)(qr + 32);
    }

    // staging lane map: 8 rows x 8 chunks per issue, chunk' = chunk ^ (row&7)
    const int srow = lane >> 3;
    const int scol = ((lane & 7) ^ srow) * 8;
    const u16* Kg0 = Kh + (size_t)(wave*16 + srow)     * HD + scol;
    const u16* Kg1 = Kh + (size_t)(wave*16 + 8 + srow) * HD + scol;
    const u16* Vg0 = Vh + (size_t)(wave*16 + srow)     * SEQ + scol;
    const u16* Vg1 = Vh + (size_t)(wave*16 + 8 + srow) * SEQ + scol;

    const int sw  = (quad ^ (l16 & 7)) * 8;            // frag chunk offset
    const int mb0 = 63 + l16 - wave*16 - quad*4 - 3;   // w-window base (>=0)

    float l_p[4] = {0.f, 0.f, 0.f, 0.f};
    f32x4 o[4];
#pragma unroll
    for (int j = 0; j < 4; ++j) o[j] = (f32x4){0.f,0.f,0.f,0.f};

    for (int kt = 0; kt < SEQ / 64; ++kt) {
        const int k0 = kt * 64;
        __syncthreads();                   // prior tile's Ks/Vs/Ps/ws2 reads done
        gload16((lptr_t)&Ks[(wave*16)*64],     Kg0 + (size_t)k0 * HD);
        gload16((lptr_t)&Ks[(wave*16 + 8)*64], Kg1 + (size_t)k0 * HD);
        gload16((lptr_t)&Vs[(wave*16)*64],     Vg0 + k0);
        gload16((lptr_t)&Vs[(wave*16 + 8)*64], Vg1 + k0);
        if (tid < 128) {                   // signed bias window, bf16 pairs
            int i0 = (q0 - k0 - 63) + tid;
            int a0 = i0 < 0 ? -i0 : i0;  if (a0 > SEQ-1) a0 = SEQ-1;
            int i1 = i0 + 1;
            int a1 = i1 < 0 ? -i1 : i1;  if (a1 > SEQ-1) a1 = SEQ-1;
            ws2[tid] = pk2(wh[a0], wh[a1]);
        }
        __syncthreads();

        // ---- S^T = K * Q^T for this wave's 16 keys; softmax; P write ----
        bf16x8 kf0 = *(const bf16x8*)&Ks[(wave*16 + l16)*64 + sw];
        bf16x8 kf1 = *(const bf16x8*)&Ks[(wave*16 + l16)*64 + (sw ^ 32)];
#pragma unroll
        for (int qj = 0; qj < 4; ++qj) {
            f32x4 z = (f32x4){0.f,0.f,0.f,0.f};
            z = __builtin_amdgcn_mfma_f32_16x16x32_bf16(kf0, qf0[qj], z, 0, 0, 0);
            z = __builtin_amdgcn_mfma_f32_16x16x32_bf16(kf1, qf1[qj], z, 0, 0, 0);
            const int mbase = mb0 + qj*16;
            u32 pA = ws2[mbase], pB = ws2[mbase + 2];
            float w3 = __uint_as_float(pA << 16);
            float w2 = __uint_as_float(pA & 0xffff0000u);
            float w1 = __uint_as_float(pB << 16);
            float w0 = __uint_as_float(pB & 0xffff0000u);
            float e0 = fexp2(z[0]) * w0, e1 = fexp2(z[1]) * w1;
            float e2 = fexp2(z[2]) * w2, e3 = fexp2(z[3]) * w3;
            l_p[qj] += (e0 + e1) + (e2 + e3);
            // 4 consecutive keys (wave*16+quad*4..+3) for q = qj*16+l16
            *(uint2*)&Ps[qj*16 + l16][wave*16 + quad*4] =
                make_uint2(pk2(e0, e1), pk2(e2, e3));
        }
        __syncthreads();                   // P visible to all waves

        // ---- PV: O[q=wave rows][d] += P * V ----
        bf16x8 pf0 = *(const bf16x8*)&Ps[wave*16 + l16][quad*8];
        bf16x8 pf1 = *(const bf16x8*)&Ps[wave*16 + l16][32 + quad*8];
#pragma unroll
        for (int j = 0; j < 4; ++j) {
            bf16x8 vf0 = *(const bf16x8*)&Vs[(j*16 + l16)*64 + sw];
            bf16x8 vf1 = *(const bf16x8*)&Vs[(j*16 + l16)*64 + (sw ^ 32)];
            o[j] = __builtin_amdgcn_mfma_f32_16x16x32_bf16(pf0, vf0, o[j], 0, 0, 0);
            o[j] = __builtin_amdgcn_mfma_f32_16x16x32_bf16(pf1, vf1, o[j], 0, 0, 0);
        }
    }

    // ---- epilogue: reduce l (quads via shfl, waves via LDS), store ----
#pragma unroll
    for (int qj = 0; qj < 4; ++qj) {
        float l = l_p[qj];
        l += __shfl_xor(l, 16);
        l += __shfl_xor(l, 32);
        if (quad == 0) lred[wave][qj*16 + l16] = l;
    }
    __syncthreads();
    if (tid < 64)
        linv[tid] = 1.0f / (lred[0][tid] + lred[1][tid] + lred[2][tid] + lred[3][tid]);
    __syncthreads();
#pragma unroll
    for (int r = 0; r < 4; ++r) {
        const int q = wave*16 + quad*4 + r;
        float inv = linv[q];
        u16* dst = attn_bf + (size_t)(b * SEQ + q0 + q) * DMODEL + h * HD;
#pragma unroll
        for (int j = 0; j < 4; ++j)
            dst[j*16 + l16] = f2bf(o[j][r] * inv);
    }
}

// ---------------------------------------------------------------------------
extern "C" void kernel_launch(void* const* d_in, const int* in_sizes, int n_in,
                              void* d_out, int out_size, void* d_ws, size_t ws_size,
                              hipStream_t stream)
{
    (void)in_sizes; (void)n_in; (void)out_size; (void)ws_size;
    const float* x      = (const float*)d_in[0];
    const float* qkv_w  = (const float*)d_in[1];
    const float* out_w  = (const float*)d_in[2];
    const float* bias_p = (const float*)d_in[3];
    const float* bias_a = (const float*)d_in[4];
    const float* freqs  = (const float*)d_in[5];
    float* out = (float*)d_out;

    // ws layout (bytes):
    //   [0, 8M)       attn_bf [4096][1024] bf16
    //   [8M, 16M)     Qb      [2][16][2048][64] bf16
    //   [24M, 32M)    x_bf    [4096][1024] bf16
    //   [32M, 38M)    w1_bf   [3072][1024] bf16
    //   [38M, 40M)    w2_bf   [1024][1024] bf16
    //   [40M, 48M)    Kb      [2][16][2048][64] bf16
    //   [48M, 56M)    Vt      [2][16][64][2048] bf16
    //   [56M, +128K)  wtab    [16][2048] f32 (exp of bias)
    //   [+128K,+640K) cs_tab  [2048][32][2] f32
    char* ws = (char*)d_ws;
    u16*   attn_bf = (u16*)ws;
    u16*   Qb      = (u16*)(ws + 8388608);
    u16*   x_bf    = (u16*)(ws + 25165824);
    u16*   w1_bf   = (u16*)(ws + 33554432);
    u16*   w2_bf   = (u16*)(ws + 39845888);
    u16*   Kb      = (u16*)(ws + 41943040);
    u16*   Vt      = (u16*)(ws + 50331648);
    float* wtab    = (float*)(ws + 58720256);
    float* cs_tab  = (float*)(ws + 58720256 + 131072);

    const int na = ROWS*DMODEL, nb = NQKV*DMODEL, nc = DMODEL*DMODEL;
    f2bf3_kernel<<<dim3((na+nb+nc)/1024), 256, 0, stream>>>(x, na, qkv_w, nb, out_w, nc,
                                                            x_bf, w1_bf, w2_bf);
    rope_table_kernel<<<dim3(SEQ*32/256), 256, 0, stream>>>(freqs, cs_tab);
    wtab_kernel<<<dim3(NH*SEQ/256), 256, 0, stream>>>(bias_p, bias_a, wtab);

    gemm_qkv<<<dim3(ROWS/128, NQKV/128), 256, 0, stream>>>(x_bf, w1_bf, cs_tab, Qb, Kb, Vt);
    attn_mfma<<<dim3(SEQ/64, NH, BATCH), 256, 0, stream>>>(Qb, Kb, Vt, wtab, attn_bf);
    gemm_out<<<dim3(ROWS/128, DMODEL/128), 256, 0, stream>>>(attn_bf, w2_bf, out, ROWS, DMODEL, DMODEL);
}

// Round 8
// 225.785 us; speedup vs baseline: 1.4398x; 1.0185x over previous
//
#include <hip/hip_runtime.h>
#include <math.h>

#define BATCH  2
#define SEQ    2048
#define DMODEL 1024
#define NH     16
#define HD     64
#define NQKV   3072
#define ROWS   (BATCH*SEQ)
#define QSCALE 0.18033688f   // 0.125 * log2(e): QK^T scores land in log2 domain

typedef unsigned short u16;
typedef unsigned int   u32;
typedef __bf16 bf16x8 __attribute__((ext_vector_type(8)));
typedef float  f32x4  __attribute__((ext_vector_type(4)));

typedef const __attribute__((address_space(1))) void* gptr_t;
typedef __attribute__((address_space(3))) void* lptr_t;

__device__ __forceinline__ void gload16(lptr_t l, const void* g) {
    __builtin_amdgcn_global_load_lds((gptr_t)g, l, 16, 0, 0);
}

__device__ __forceinline__ u16 f2bf(float f) {          // RNE f32->bf16
    unsigned int u = __float_as_uint(f);
    u += 0x7FFFu + ((u >> 16) & 1u);
    return (u16)(u >> 16);
}
__device__ __forceinline__ u32 pk2(float lo, float hi) { // pack 2 f32 -> 2 bf16
#if __has_builtin(__builtin_amdgcn_cvt_pk_bf16_f32)
    typedef __bf16 bf16x2 __attribute__((ext_vector_type(2)));
    union { bf16x2 v; u32 u; } cv;
    cv.v = __builtin_amdgcn_cvt_pk_bf16_f32(lo, hi);
    return cv.u;
#else
    return (u32)f2bf(lo) | ((u32)f2bf(hi) << 16);
#endif
}
__device__ __forceinline__ float fexp2(float x) {
#if __has_builtin(__builtin_amdgcn_exp2f)
    return __builtin_amdgcn_exp2f(x);
#else
    return exp2f(x);
#endif
}

// ---------------------------------------------------------------------------
// fused prep: f32->bf16 for x/qkv_w/out_w, rope cos/sin table, bias wtab.
// Blocks [0, NBC): convert; [NBC, NBC+256): rope table; [NBC+256, +128): wtab.
// ---------------------------------------------------------------------------
#define NBC ((ROWS*DMODEL + NQKV*DMODEL + DMODEL*DMODEL) / 1024)
__global__ void prep_kernel(const float* __restrict__ a,
                            const float* __restrict__ b,
                            const float* __restrict__ c,
                            u16* __restrict__ oa, u16* __restrict__ ob,
                            u16* __restrict__ oc,
                            const float* __restrict__ freqs, float* __restrict__ cs_tab,
                            const float* __restrict__ bias_p,
                            const float* __restrict__ bias_a,
                            float* __restrict__ wtab)
{
    const int na = ROWS*DMODEL, nb = NQKV*DMODEL;
    int blk = blockIdx.x;
    if (blk < NBC) {
        int i = (blk * 256 + threadIdx.x) * 4;
        const float* s; u16* d; int base;
        if (i < na)           { s = a; d = oa; base = i; }
        else if (i < na + nb) { s = b; d = ob; base = i - na; }
        else                  { s = c; d = oc; base = i - na - nb; }
        float4 v = *(const float4*)(s + base);
        u16 o[4] = { f2bf(v.x), f2bf(v.y), f2bf(v.z), f2bf(v.w) };
        *(uint2*)(d + base) = *(const uint2*)o;
    } else if (blk < NBC + 256) {
        int idx = (blk - NBC) * 256 + threadIdx.x;   // SEQ*32
        int s = idx >> 5, d = idx & 31;
        float sn, cs;
        sincosf((float)s * freqs[d], &sn, &cs);
        cs_tab[idx * 2]     = cs;
        cs_tab[idx * 2 + 1] = sn;
    } else {
        int idx = (blk - NBC - 256) * 256 + threadIdx.x;  // NH*SEQ
        int h = idx >> 11;
        int d = idx & (SEQ - 1);
        float p = fmaxf(bias_p[h], 0.01f);
        float aa = fmaxf(bias_a[h], 0.01f);
        wtab[idx] = __expf(-p * log1pf(aa * (float)d));
    }
}

// ---------------------------------------------------------------------------
// QKV GEMM with fused RoPE + layout epilogue (verified R6/R7). 128x128 tile.
// ---------------------------------------------------------------------------
__global__ __launch_bounds__(256) void gemm_qkv(
    const u16* __restrict__ A, const u16* __restrict__ B,
    const float* __restrict__ cs_tab,
    u16* __restrict__ Qb, u16* __restrict__ Kb, u16* __restrict__ Vt)
{
    const int K = DMODEL;
    __shared__ __align__(16) u16 As[128][32];
    __shared__ __align__(16) u16 Bs[128][32];
    const int tid  = threadIdx.x;
    const int wave = tid >> 6, lane = tid & 63;
    const int quad = lane >> 4, l16 = lane & 15;
    const int wrow = (wave >> 1) * 64, wcol = (wave & 1) * 64;
    const int bm = blockIdx.x * 128, bn = blockIdx.y * 128;

    const int srow = lane >> 2;                       // 0..15
    const int scol = ((lane & 3) ^ (srow & 3)) * 8;   // swizzled chunk (u16)
    const int fsw = (quad ^ (l16 & 3)) * 8;           // frag read swizzle

    f32x4 acc[4][4];
#pragma unroll
    for (int i = 0; i < 4; ++i)
#pragma unroll
        for (int j = 0; j < 4; ++j) acc[i][j] = (f32x4){0.f,0.f,0.f,0.f};

    const u16* Ag0 = A + (size_t)(bm + wave*32 + srow)      * K + scol;
    const u16* Ag1 = A + (size_t)(bm + wave*32 + 16 + srow) * K + scol;
    const u16* Bg0 = B + (size_t)(bn + wave*32 + srow)      * K + scol;
    const u16* Bg1 = B + (size_t)(bn + wave*32 + 16 + srow) * K + scol;

    for (int k0 = 0; k0 < K; k0 += 32) {
        __syncthreads();
        gload16((lptr_t)&As[wave*32][0],      Ag0 + k0);
        gload16((lptr_t)&As[wave*32 + 16][0], Ag1 + k0);
        gload16((lptr_t)&Bs[wave*32][0],      Bg0 + k0);
        gload16((lptr_t)&Bs[wave*32 + 16][0], Bg1 + k0);
        __syncthreads();
        bf16x8 af[4], bfr[4];
#pragma unroll
        for (int i = 0; i < 4; ++i)
            af[i] = *(const bf16x8*)&As[wrow + i*16 + l16][fsw];
#pragma unroll
        for (int j = 0; j < 4; ++j)
            bfr[j] = *(const bf16x8*)&Bs[wcol + j*16 + l16][fsw];
#pragma unroll
        for (int i = 0; i < 4; ++i)
#pragma unroll
            for (int j = 0; j < 4; ++j)
                acc[i][j] = __builtin_amdgcn_mfma_f32_16x16x32_bf16(af[i], bfr[j], acc[i][j], 0, 0, 0);
    }

    // ---- fused epilogue ----
    const int tcol = (bn + wcol) >> 6;          // global 64-col index, 0..47
    const int t = tcol >> 4, h = tcol & 15;     // tensor (q/k/v), head
    const int bq = bm >> 11;                    // batch (tile never crosses)
    const int sb = (bm & (SEQ - 1)) + wrow;     // s base of this quadrant
    const size_t hb = (size_t)(bq * NH + h) * SEQ * HD;

    if (t == 2) {
#pragma unroll
        for (int i = 0; i < 4; ++i) {
            const int s = sb + i*16 + quad*4;
#pragma unroll
            for (int j = 0; j < 4; ++j) {
                const int d = j*16 + l16;
                uint2 pv = make_uint2(pk2(acc[i][j][0], acc[i][j][1]),
                                      pk2(acc[i][j][2], acc[i][j][3]));
                *(uint2*)&Vt[hb + (size_t)d * SEQ + s] = pv;
            }
        }
    } else {
        const float sc = (t == 0) ? QSCALE : 1.0f;
        u16* dstb = ((t == 0) ? Qb : Kb) + hb;
#pragma unroll
        for (int i = 0; i < 4; ++i) {
#pragma unroll
            for (int r = 0; r < 4; ++r) {
                const int s = sb + i*16 + quad*4 + r;
                const float2* ct = (const float2*)(cs_tab + ((size_t)s * 32 + l16) * 2);
                float2 cs0 = ct[0];     // freq idx l16
                float2 cs1 = ct[16];    // freq idx l16+16
                float a0 = acc[i][0][r], a1 = acc[i][1][r];
                float a2 = acc[i][2][r], a3 = acc[i][3][r];
                u16* dst = dstb + (size_t)s * HD;
                dst[l16]      = f2bf((a0*cs0.x - a2*cs0.y) * sc);
                dst[16 + l16] = f2bf((a1*cs1.x - a3*cs1.y) * sc);
                dst[32 + l16] = f2bf((a0*cs0.y + a2*cs0.x) * sc);
                dst[48 + l16] = f2bf((a1*cs1.y + a3*cs1.x) * sc);
            }
        }
    }
}

// ---------------------------------------------------------------------------
// out-projection GEMM: 128x64 tile (M x N) -> 512 blocks = 2+/CU for overlap.
// Wave w: rows (w>>1)*64, cols (w&1)*32. LDS 12 KB.
// ---------------------------------------------------------------------------
__global__ __launch_bounds__(256) void gemm_out(
    const u16* __restrict__ A, const u16* __restrict__ B,
    float* __restrict__ Cout, int M, int N, int K)
{
    __shared__ __align__(16) u16 As[128][32];
    __shared__ __align__(16) u16 Bs[64][32];
    const int tid  = threadIdx.x;
    const int wave = tid >> 6, lane = tid & 63;
    const int quad = lane >> 4, l16 = lane & 15;
    const int wrow = (wave >> 1) * 64, wcol = (wave & 1) * 32;
    const int bm = blockIdx.x * 128, bn = blockIdx.y * 64;

    const int srow = lane >> 2;
    const int scol = ((lane & 3) ^ (srow & 3)) * 8;
    const int fsw = (quad ^ (l16 & 3)) * 8;

    f32x4 acc[4][2];
#pragma unroll
    for (int i = 0; i < 4; ++i)
#pragma unroll
        for (int j = 0; j < 2; ++j) acc[i][j] = (f32x4){0.f,0.f,0.f,0.f};

    const u16* Ag0 = A + (size_t)(bm + wave*32 + srow)      * K + scol;
    const u16* Ag1 = A + (size_t)(bm + wave*32 + 16 + srow) * K + scol;
    const u16* Bg0 = B + (size_t)(bn + wave*16 + srow)      * K + scol;

    for (int k0 = 0; k0 < K; k0 += 32) {
        __syncthreads();
        gload16((lptr_t)&As[wave*32][0],      Ag0 + k0);
        gload16((lptr_t)&As[wave*32 + 16][0], Ag1 + k0);
        gload16((lptr_t)&Bs[wave*16][0],      Bg0 + k0);
        __syncthreads();
        bf16x8 af[4], bfr[2];
#pragma unroll
        for (int i = 0; i < 4; ++i)
            af[i] = *(const bf16x8*)&As[wrow + i*16 + l16][fsw];
#pragma unroll
        for (int j = 0; j < 2; ++j)
            bfr[j] = *(const bf16x8*)&Bs[wcol + j*16 + l16][fsw];
#pragma unroll
        for (int i = 0; i < 4; ++i)
#pragma unroll
            for (int j = 0; j < 2; ++j)
                acc[i][j] = __builtin_amdgcn_mfma_f32_16x16x32_bf16(af[i], bfr[j], acc[i][j], 0, 0, 0);
    }

#pragma unroll
    for (int i = 0; i < 4; ++i)
#pragma unroll
        for (int j = 0; j < 2; ++j) {
            int col = bn + wcol + j*16 + l16;
#pragma unroll
            for (int r = 0; r < 4; ++r) {
                int row = bm + wrow + i*16 + quad*4 + r;
                Cout[(size_t)row * N + col] = acc[i][j][r];
            }
        }
}

// ---------------------------------------------------------------------------
// MFMA flash attention v5: R5/R7 structure, key-tile 128 (half the barriers
// and bias-window fills; per-key LDS/MFMA/VALU identical). Wave w owns keys
// w*32..+31 of each 128-key tile (2 groups of 16).
// ---------------------------------------------------------------------------
__global__ __launch_bounds__(256) void attn_mfma(
    const u16* __restrict__ Qb, const u16* __restrict__ Kb,
    const u16* __restrict__ Vt, const float* __restrict__ wtab,
    u16* __restrict__ attn_bf)
{
    __shared__ __align__(16) u16 Ks[128*64];   // [key][d], 8-chunk rows, swizzled
    __shared__ __align__(16) u16 Vs[64*128];   // [d][key], 16-chunk rows, swizzled
    __shared__ __align__(16) u16 Ps[64][136];  // [q][key], padded
    __shared__ u32 ws2[192];                   // packed {w[m], w[m+1]}
    __shared__ float lred[4][64];
    __shared__ float linv[64];

    const int tid = threadIdx.x;
    const int wave = tid >> 6, lane = tid & 63;
    const int quad = lane >> 4, l16 = lane & 15;
    const int q0 = blockIdx.x * 64, h = blockIdx.y, b = blockIdx.z;

    const u16* Qh = Qb + (size_t)(b * NH + h) * SEQ * HD;
    const u16* Kh = Kb + (size_t)(b * NH + h) * SEQ * HD;
    const u16* Vh = Vt + (size_t)(b * NH + h) * HD * SEQ;
    const float* wh = wtab + h * SEQ;

    // Q fragments (B-operand of S^T): all 64 q rows per wave, in registers
    bf16x8 qf0[4], qf1[4];
#pragma unroll
    for (int qj = 0; qj < 4; ++qj) {
        const u16* qr = Qh + (size_t)(q0 + qj*16 + l16) * HD + quad * 8;
        qf0[qj] = *(const bf16x8*)qr;
        qf1[qj] = *(const bf16x8*)(qr + 32);
    }

    // K staging: 4 issues, 8 rows x 8 chunks each; chunk' = chunk ^ (row&7)
    const int ksrow = lane >> 3;                       // 0..7
    const int kscol = ((lane & 7) ^ ksrow) * 8;
    const u16* Kst[4];
#pragma unroll
    for (int i = 0; i < 4; ++i)
        Kst[i] = Kh + (size_t)(wave*32 + i*8 + ksrow) * HD + kscol;

    // V staging: 4 issues, 4 rows x 16 chunks each; chunk' = chunk ^ (d&7)
    const int vsrow = lane >> 4;                       // 0..3
    const u16* Vst[4];
    int vscol[4];
#pragma unroll
    for (int i = 0; i < 4; ++i) {
        int d = wave*16 + i*4 + vsrow;
        vscol[i] = ((lane & 15) ^ (d & 7)) * 8;
        Vst[i] = Vh + (size_t)d * SEQ + vscol[i];
    }

    const int sw  = (quad ^ (l16 & 7)) * 8;            // kf chunk offset
    const int mb0 = 127 + l16 - wave*32 - quad*4 - 3;  // w-window base (>=0)

    float l_p[4] = {0.f, 0.f, 0.f, 0.f};
    f32x4 o[4];
#pragma unroll
    for (int j = 0; j < 4; ++j) o[j] = (f32x4){0.f,0.f,0.f,0.f};

    for (int kt = 0; kt < SEQ / 128; ++kt) {
        const int k0 = kt * 128;
        __syncthreads();                   // prior tile's Ks/Vs/Ps/ws2 reads done
#pragma unroll
        for (int i = 0; i < 4; ++i) {
            gload16((lptr_t)&Ks[(wave*32 + i*8)*64],  Kst[i] + (size_t)k0 * HD);
            gload16((lptr_t)&Vs[(wave*16 + i*4)*128], Vst[i] + k0);
        }
        if (tid < 192) {                   // signed bias window, bf16 pairs
            int i0 = (q0 - k0 - 127) + tid;
            int a0 = i0 < 0 ? -i0 : i0;  if (a0 > SEQ-1) a0 = SEQ-1;
            int i1 = i0 + 1;
            int a1 = i1 < 0 ? -i1 : i1;  if (a1 > SEQ-1) a1 = SEQ-1;
            ws2[tid] = pk2(wh[a0], wh[a1]);
        }
        __syncthreads();

        // ---- S^T = K * Q^T for this wave's 2x16 keys; softmax; P write ----
#pragma unroll
        for (int kg = 0; kg < 2; ++kg) {
            const int krow = (wave*32 + kg*16 + l16) * 64;
            bf16x8 kf0 = *(const bf16x8*)&Ks[krow + sw];
            bf16x8 kf1 = *(const bf16x8*)&Ks[krow + (sw ^ 32)];
#pragma unroll
            for (int qj = 0; qj < 4; ++qj) {
                f32x4 z = (f32x4){0.f,0.f,0.f,0.f};
                z = __builtin_amdgcn_mfma_f32_16x16x32_bf16(kf0, qf0[qj], z, 0, 0, 0);
                z = __builtin_amdgcn_mfma_f32_16x16x32_bf16(kf1, qf1[qj], z, 0, 0, 0);
                const int mbase = mb0 + qj*16 - kg*16;
                u32 pA = ws2[mbase], pB = ws2[mbase + 2];
                float w3 = __uint_as_float(pA << 16);
                float w2 = __uint_as_float(pA & 0xffff0000u);
                float w1 = __uint_as_float(pB << 16);
                float w0 = __uint_as_float(pB & 0xffff0000u);
                float e0 = fexp2(z[0]) * w0, e1 = fexp2(z[1]) * w1;
                float e2 = fexp2(z[2]) * w2, e3 = fexp2(z[3]) * w3;
                l_p[qj] += (e0 + e1) + (e2 + e3);
                *(uint2*)&Ps[qj*16 + l16][wave*32 + kg*16 + quad*4] =
                    make_uint2(pk2(e0, e1), pk2(e2, e3));
            }
        }
        __syncthreads();                   // P visible to all waves

        // ---- PV: O[q=wave rows][d] += P * V over 128 keys ----
        bf16x8 pf[4];
#pragma unroll
        for (int m = 0; m < 4; ++m)
            pf[m] = *(const bf16x8*)&Ps[wave*16 + l16][m*32 + quad*8];
#pragma unroll
        for (int j = 0; j < 4; ++j) {
            const int vrow = (j*16 + l16) * 128;
            const int vsw = l16 & 7;
#pragma unroll
            for (int m = 0; m < 4; ++m) {
                bf16x8 vf = *(const bf16x8*)&Vs[vrow + (((m*4 + quad) ^ vsw) * 8)];
                o[j] = __builtin_amdgcn_mfma_f32_16x16x32_bf16(pf[m], vf, o[j], 0, 0, 0);
            }
        }
    }

    // ---- epilogue: reduce l (quads via shfl, waves via LDS), store ----
#pragma unroll
    for (int qj = 0; qj < 4; ++qj) {
        float l = l_p[qj];
        l += __shfl_xor(l, 16);
        l += __shfl_xor(l, 32);
        if (quad == 0) lred[wave][qj*16 + l16] = l;
    }
    __syncthreads();
    if (tid < 64)
        linv[tid] = 1.0f / (lred[0][tid] + lred[1][tid] + lred[2][tid] + lred[3][tid]);
    __syncthreads();
#pragma unroll
    for (int r = 0; r < 4; ++r) {
        const int q = wave*16 + quad*4 + r;
        float inv = linv[q];
        u16* dst = attn_bf + (size_t)(b * SEQ + q0 + q) * DMODEL + h * HD;
#pragma unroll
        for (int j = 0; j < 4; ++j)
            dst[j*16 + l16] = f2bf(o[j][r] * inv);
    }
}

// ---------------------------------------------------------------------------
extern "C" void kernel_launch(void* const* d_in, const int* in_sizes, int n_in,
                              void* d_out, int out_size, void* d_ws, size_t ws_size,
                              hipStream_t stream)
{
    (void)in_sizes; (void)n_in; (void)out_size; (void)ws_size;
    const float* x      = (const float*)d_in[0];
    const float* qkv_w  = (const float*)d_in[1];
    const float* out_w  = (const float*)d_in[2];
    const float* bias_p = (const float*)d_in[3];
    const float* bias_a = (const float*)d_in[4];
    const float* freqs  = (const float*)d_in[5];
    float* out = (float*)d_out;

    // ws layout (bytes):
    //   [0, 8M)       attn_bf [4096][1024] bf16
    //   [8M, 16M)     Qb      [2][16][2048][64] bf16
    //   [24M, 32M)    x_bf    [4096][1024] bf16
    //   [32M, 38M)    w1_bf   [3072][1024] bf16
    //   [38M, 40M)    w2_bf   [1024][1024] bf16
    //   [40M, 48M)    Kb      [2][16][2048][64] bf16
    //   [48M, 56M)    Vt      [2][16][64][2048] bf16
    //   [56M, +128K)  wtab    [16][2048] f32 (exp of bias)
    //   [+128K,+640K) cs_tab  [2048][32][2] f32
    char* ws = (char*)d_ws;
    u16*   attn_bf = (u16*)ws;
    u16*   Qb      = (u16*)(ws + 8388608);
    u16*   x_bf    = (u16*)(ws + 25165824);
    u16*   w1_bf   = (u16*)(ws + 33554432);
    u16*   w2_bf   = (u16*)(ws + 39845888);
    u16*   Kb      = (u16*)(ws + 41943040);
    u16*   Vt      = (u16*)(ws + 50331648);
    float* wtab    = (float*)(ws + 58720256);
    float* cs_tab  = (float*)(ws + 58720256 + 131072);

    prep_kernel<<<dim3(NBC + 256 + 128), 256, 0, stream>>>(
        x, qkv_w, out_w, x_bf, w1_bf, w2_bf, freqs, cs_tab, bias_p, bias_a, wtab);

    gemm_qkv<<<dim3(ROWS/128, NQKV/128), 256, 0, stream>>>(x_bf, w1_bf, cs_tab, Qb, Kb, Vt);
    attn_mfma<<<dim3(SEQ/64, NH, BATCH), 256, 0, stream>>>(Qb, Kb, Vt, wtab, attn_bf);
    gemm_out<<<dim3(ROWS/128, DMODEL/64), 256, 0, stream>>>(attn_bf, w2_bf, out, ROWS, DMODEL, DMODEL);
}